// Round 1
// baseline (416.309 us; speedup 1.0000x reference)
//
#include <hip/hip_runtime.h>

// BFP quantization: blocks of 16 consecutive floats along last dim share one
// exponent (floor(log2(max|x|))), 8-bit signed mantissa (qmin=-128, qmax=127).
// One thread per float4; 4 consecutive lanes cooperate on one 16-elem block
// via __shfl_xor quad reduction. Pure streaming kernel, HBM-bound.

__global__ __launch_bounds__(256) void bfp_quant_kernel(
    const float4* __restrict__ x, float4* __restrict__ out, int n4) {
    int idx = blockIdx.x * blockDim.x + threadIdx.x;
    if (idx >= n4) return;

    float4 v = x[idx];

    // per-lane max |.| over 4 elements
    float m = fmaxf(fmaxf(fabsf(v.x), fabsf(v.y)),
                    fmaxf(fabsf(v.z), fabsf(v.w)));
    // reduce across the aligned quad of lanes (one 16-elem BFP block)
    m = fmaxf(m, __shfl_xor(m, 1));
    m = fmaxf(m, __shfl_xor(m, 2));

    // safe_max guard identical to reference: zero block -> scale from 1.0,
    // all values 0 so output is exactly 0 (no inf/NaN path).
    float sm = (m > 0.0f) ? m : 1.0f;

    // floor(log2(sm)) for normal floats = unbiased exponent field
    int e = (int)(__float_as_uint(sm) >> 23) - 127;

    float scale = ldexpf(1.0f, e - 7);   // 2^(e - (mantissa_bits-1))
    float inv   = ldexpf(1.0f, 7 - e);   // exact reciprocal (power of 2)

    float4 q;
    q.x = fminf(fmaxf(rintf(v.x * inv), -128.0f), 127.0f) * scale;
    q.y = fminf(fmaxf(rintf(v.y * inv), -128.0f), 127.0f) * scale;
    q.z = fminf(fmaxf(rintf(v.z * inv), -128.0f), 127.0f) * scale;
    q.w = fminf(fmaxf(rintf(v.w * inv), -128.0f), 127.0f) * scale;

    out[idx] = q;
}

extern "C" void kernel_launch(void* const* d_in, const int* in_sizes, int n_in,
                              void* d_out, int out_size, void* d_ws, size_t ws_size,
                              hipStream_t stream) {
    const float* x = (const float*)d_in[0];
    float* out = (float*)d_out;
    int n = in_sizes[0];          // 4*4096*4096 = 67108864, divisible by 4
    int n4 = n >> 2;

    const int threads = 256;
    int blocks = (n4 + threads - 1) / threads;
    bfp_quant_kernel<<<blocks, threads, 0, stream>>>(
        (const float4*)x, (float4*)out, n4);
}